// Round 2
// 150.060 us; speedup vs baseline: 1.0269x; 1.0269x over previous
//
#include <hip/hip_runtime.h>
#include <hip/hip_bf16.h>
#include <math.h>

#define BB   2
#define MM   2048      // l*n
#define DIM  512
#define NH   8
#define DHd  64
#define NQK  1536
#define ROWS 4096      // BB*MM
#define NROW 32768     // 16 bh * 2048 rows (rows per split-K partial)
#define SPLITK 4

typedef __hip_bfloat16 bf16;
typedef __attribute__((ext_vector_type(8))) short bf16x8;
typedef __attribute__((ext_vector_type(4))) float f32x4;
typedef __attribute__((ext_vector_type(8))) unsigned short us8;

__device__ __forceinline__ unsigned short f2bf_bits(float x) {
    bf16 h = __float2bfloat16(x);
    return *(unsigned short*)&h;
}
__device__ __forceinline__ float bf2f(unsigned short u) {
    unsigned int v = ((unsigned int)u) << 16;
    return __uint_as_float(v);
}

// ---- fused pre-pass: LayerNorm (blocks 0..4095) + weight transposes -------
__global__ __launch_bounds__(256) void pre_kernel(
    const float* __restrict__ feat, const float* __restrict__ gamma,
    const float* __restrict__ beta, unsigned short* __restrict__ normed,
    const float* __restrict__ wqkv, const float* __restrict__ wout,
    unsigned short* __restrict__ wqkvT, unsigned short* __restrict__ woutT)
{
    __shared__ float st[64][65];
    int b = blockIdx.x;
    int tid = threadIdx.x;
    if (b < ROWS) {
        // ---- LayerNorm row b -> bf16
        const float* fr = feat + (size_t)b * DIM;
        float x0 = fr[tid];
        float x1 = fr[tid + 256];
        float s  = x0 + x1;
        float ss = x0 * x0 + x1 * x1;
        #pragma unroll
        for (int o = 32; o >= 1; o >>= 1) { s += __shfl_down(s, o); ss += __shfl_down(ss, o); }
        __shared__ float ws_[4], wss_[4];
        int wid = tid >> 6, lane = tid & 63;
        if (lane == 0) { ws_[wid] = s; wss_[wid] = ss; }
        __syncthreads();
        if (tid == 0) {
            float a = 0.f, c = 0.f;
            for (int i = 0; i < 4; i++) { a += ws_[i]; c += wss_[i]; }
            ws_[0] = a; wss_[0] = c;
        }
        __syncthreads();
        float mu  = ws_[0] * (1.0f / DIM);
        float var = wss_[0] * (1.0f / DIM) - mu * mu;
        float inv = rsqrtf(var + 1e-5f);
        normed[(size_t)b * DIM + tid]       = f2bf_bits((x0 - mu) * inv * gamma[tid] + beta[tid]);
        normed[(size_t)b * DIM + tid + 256] = f2bf_bits((x1 - mu) * inv * gamma[tid + 256] + beta[tid + 256]);
        return;
    }
    // ---- weight transpose: out[n][k] = bf16(in[k][n])
    int idx = b - ROWS;
    const float* in; unsigned short* out; int N, n0;
    if (idx < 192) { in = wqkv; out = wqkvT; N = NQK; n0 = (idx >> 3) * 64; }
    else { idx -= 192; in = wout; out = woutT; N = DIM; n0 = (idx >> 3) * 64; }
    int k0 = (idx & 7) * 64;
    #pragma unroll
    for (int p = 0; p < 16; p++) {
        int e = tid + p * 256;
        int r = e >> 6, c = e & 63;
        st[r][c] = in[(size_t)(k0 + r) * N + n0 + c];
    }
    __syncthreads();
    #pragma unroll
    for (int p = 0; p < 16; p++) {
        int e = tid + p * 256;
        int nr = e >> 6, kc = e & 63;
        out[(size_t)(n0 + nr) * DIM + k0 + kc] = f2bf_bits(st[kc][nr]);
    }
}

// ---- QKV GEMM (MFMA): q/k blocks computed transposed (A=weights) so the
//      accumulator's reg axis lands on d -> ushort4 stores.
__global__ __launch_bounds__(256) void qkv_gemm(
    const unsigned short* __restrict__ A, const unsigned short* __restrict__ BT,
    unsigned short* __restrict__ qd, unsigned short* __restrict__ kd,
    unsigned short* __restrict__ vd)
{
    __shared__ __align__(16) unsigned short sA[128 * 40];
    __shared__ __align__(16) unsigned short sB[128 * 40];
    int tid = threadIdx.x;
    int r0 = blockIdx.x * 128;
    int n0 = blockIdx.y * 128;
    int chunk = n0 >> 9;           // 0=q 1=k 2=v
    int cl    = n0 & 511;
    int w = tid >> 6, lane = tid & 63;
    int wm = w >> 1, wn = w & 1;
    int ln15 = lane & 15, quad = lane >> 4;

    int srow = tid >> 1;
    int scol = (tid & 1) * 16;

    f32x4 acc[4][4] = {};

    for (int k0 = 0; k0 < DIM; k0 += 32) {
        __syncthreads();
        *(us8*)&sA[srow * 40 + scol]     = *(const us8*)&A[(size_t)(r0 + srow) * DIM + k0 + scol];
        *(us8*)&sA[srow * 40 + scol + 8] = *(const us8*)&A[(size_t)(r0 + srow) * DIM + k0 + scol + 8];
        *(us8*)&sB[srow * 40 + scol]     = *(const us8*)&BT[(size_t)(n0 + srow) * DIM + k0 + scol];
        *(us8*)&sB[srow * 40 + scol + 8] = *(const us8*)&BT[(size_t)(n0 + srow) * DIM + k0 + scol + 8];
        __syncthreads();
        const unsigned short* fa = (chunk == 2) ? sA : sB;
        const unsigned short* fb = (chunk == 2) ? sB : sA;
        bf16x8 af[4], bf_[4];
        #pragma unroll
        for (int i = 0; i < 4; i++)
            af[i] = *(const bf16x8*)&fa[(wm * 64 + i * 16 + ln15) * 40 + quad * 8];
        #pragma unroll
        for (int j = 0; j < 4; j++)
            bf_[j] = *(const bf16x8*)&fb[(wn * 64 + j * 16 + ln15) * 40 + quad * 8];
        #pragma unroll
        for (int i = 0; i < 4; i++)
            #pragma unroll
            for (int j = 0; j < 4; j++)
                acc[i][j] = __builtin_amdgcn_mfma_f32_16x16x32_bf16(af[i], bf_[j], acc[i][j], 0, 0, 0);
    }

    if (chunk == 2) {
        int rowb = r0 + wm * 64 + quad * 4;
        #pragma unroll
        for (int j = 0; j < 4; j++) {
            int c = cl + wn * 64 + j * 16 + ln15;
            int h = c >> 6, d = c & 63;
            #pragma unroll
            for (int i = 0; i < 4; i++) {
                int gr = rowb + i * 16;
                int bb = gr >> 11, mm = gr & 2047;
                ushort4 pk;
                pk.x = f2bf_bits(acc[i][j][0]);
                pk.y = f2bf_bits(acc[i][j][1]);
                pk.z = f2bf_bits(acc[i][j][2]);
                pk.w = f2bf_bits(acc[i][j][3]);
                *(ushort4*)&vd[((size_t)(bb * NH + h) * DHd + d) * MM + mm] = pk;
            }
        }
    } else {
        unsigned short* dst = (chunk == 0) ? qd : kd;
        float sc = (chunk == 0) ? 0.125f : 1.0f;
        #pragma unroll
        for (int i = 0; i < 4; i++) {
            int within0 = cl + wm * 64 + i * 16 + quad * 4;
            int h = within0 >> 6, d = within0 & 63;
            #pragma unroll
            for (int j = 0; j < 4; j++) {
                int gr = r0 + wn * 64 + j * 16 + ln15;
                int bb = gr >> 11, mm = gr & 2047;
                ushort4 pk;
                pk.x = f2bf_bits(acc[i][j][0] * sc);
                pk.y = f2bf_bits(acc[i][j][1] * sc);
                pk.z = f2bf_bits(acc[i][j][2] * sc);
                pk.w = f2bf_bits(acc[i][j][3] * sc);
                *(ushort4*)&dst[((size_t)(bb * NH + h) * MM + mm) * DHd + d] = pk;
            }
        }
    }
}

// ---------------- MFMA flash attention v2 ----------------------------------
// 32 Q-rows per wave (2 row-frags) -> K/V fragment reads amortized 2x.
// Q fragments loaded directly from global (no sQ). Split-K = 4 keeps the
// grid at 1024 blocks (4 blocks/CU, 16 waves/CU; LDS 39.2KB -> 4 blocks).
// No online max (S bounded by construction; shift-invariant softmax, m=0).
// V extended: cols 64..66 = key xyz, col 67 = 1.0 (gives l), 68..79 = 0.
// K/V/xyz for tile j+1 prefetched into VGPRs during tile j's compute.
__global__ __launch_bounds__(256, 4) void attn_kernel(
    const unsigned short* __restrict__ qg, const unsigned short* __restrict__ kg,
    const unsigned short* __restrict__ vg, const float* __restrict__ xyzs,
    unsigned short* __restrict__ obuf, float* __restrict__ lbuf)
{
    __shared__ __align__(16) unsigned short sK[64 * 72];
    __shared__ __align__(16) unsigned short sVT[80 * 72];
    __shared__ __align__(16) unsigned short sP[128 * 72];

    int tid = threadIdx.x;
    int bh = blockIdx.y; int bb = bh >> 3;
    int i0 = blockIdx.x * 128;
    int ks = blockIdx.z;
    int w = tid >> 6;
    int lane = tid & 63;
    int ln15 = lane & 15;
    int quad = lane >> 4;

    // one-time inits: zero pad rows 68..79, ones row 67
    for (int e = tid; e < 12 * 72; e += 256) sVT[68 * 72 + e] = 0;
    if (tid < 64) sVT[67 * 72 + tid] = 0x3F80;   // bf16 1.0

    // Q fragments direct from global (row-major [row][d] matches A-frag)
    bf16x8 aq[2][2];
    {
        const unsigned short* q0 = qg + ((size_t)bh * MM + i0 + w * 32 + ln15) * DHd + quad * 8;
        aq[0][0] = *(const bf16x8*)q0;
        aq[0][1] = *(const bf16x8*)(q0 + 32);
        aq[1][0] = *(const bf16x8*)(q0 + 16 * DHd);
        aq[1][1] = *(const bf16x8*)(q0 + 16 * DHd + 32);
    }

    f32x4 o[2][5] = {};   // t=0..3: V cols; t=4: [x,y,z,l] at ln15=0..3

    const unsigned short* kbase = kg + (size_t)bh * MM * DHd;
    const unsigned short* vbase = vg + (size_t)bh * DHd * MM;
    int jbeg = ks * (MM / SPLITK), jend = jbeg + (MM / SPLITK);

    int srow = tid >> 2, scol16 = (tid & 3) * 16;   // staging coords (K and VT)

    us8 rk0, rk1, rv0, rv1;
    float rx = 0.f;
    {   // preload first tile
        const unsigned short* src = kbase + (size_t)jbeg * DHd;
        rk0 = *(const us8*)&src[(size_t)tid * 16];
        rk1 = *(const us8*)&src[(size_t)tid * 16 + 8];
        const unsigned short* vs = vbase + jbeg;
        rv0 = *(const us8*)&vs[(size_t)srow * MM + scol16];
        rv1 = *(const us8*)&vs[(size_t)srow * MM + scol16 + 8];
        if (tid < 192) rx = xyzs[((size_t)bb * MM + jbeg) * 3 + tid];
    }

    int pwb = quad << 4;                       // write-side swizzle for sP
    int swzr = (ln15 >> 2) << 4;               // read-side swizzle
    int pr0 = (quad * 8) ^ swzr;
    int pr1 = (32 + quad * 8) ^ swzr;

    for (int jt = jbeg; jt < jend; jt += 64) {
        __syncthreads();
        // commit prefetched tile to LDS
        *(us8*)&sK[srow * 72 + scol16]      = rk0;
        *(us8*)&sK[srow * 72 + scol16 + 8]  = rk1;
        *(us8*)&sVT[srow * 72 + scol16]     = rv0;
        *(us8*)&sVT[srow * 72 + scol16 + 8] = rv1;
        if (tid < 192) {
            int key = tid / 3, c = tid - key * 3;
            sVT[(64 + c) * 72 + key] = f2bf_bits(rx);
        }
        __syncthreads();
        // issue prefetch for next tile (consumed next iteration)
        int jn = jt + 64;
        if (jn < jend) {
            const unsigned short* src = kbase + (size_t)jn * DHd;
            rk0 = *(const us8*)&src[(size_t)tid * 16];
            rk1 = *(const us8*)&src[(size_t)tid * 16 + 8];
            const unsigned short* vs = vbase + jn;
            rv0 = *(const us8*)&vs[(size_t)srow * MM + scol16];
            rv1 = *(const us8*)&vs[(size_t)srow * MM + scol16 + 8];
            if (tid < 192) rx = xyzs[((size_t)bb * MM + jn) * 3 + tid];
        }

        // QK^T: K fragments loaded once per t, reused for both row-frags.
        // exp + packed-bf16 P write fused per (t, rf) so S never persists.
        #pragma unroll
        for (int t = 0; t < 4; t++) {
            bf16x8 bk0 = *(const bf16x8*)&sK[(t * 16 + ln15) * 72 + quad * 8];
            bf16x8 bk1 = *(const bf16x8*)&sK[(t * 16 + ln15) * 72 + 32 + quad * 8];
            int colb = (t * 16) ^ pwb;
            #pragma unroll
            for (int rf = 0; rf < 2; rf++) {
                f32x4 z = {};
                z = __builtin_amdgcn_mfma_f32_16x16x32_bf16(aq[rf][0], bk0, z, 0, 0, 0);
                z = __builtin_amdgcn_mfma_f32_16x16x32_bf16(aq[rf][1], bk1, z, 0, 0, 0);
                int rbase = (w * 32 + rf * 16 + quad * 4) * 72 + colb + ln15;
                sP[rbase]           = f2bf_bits(__expf(z[0]));
                sP[rbase + 72]      = f2bf_bits(__expf(z[1]));
                sP[rbase + 144]     = f2bf_bits(__expf(z[2]));
                sP[rbase + 216]     = f2bf_bits(__expf(z[3]));
            }
        }
        asm volatile("s_waitcnt lgkmcnt(0)" ::: "memory");
        bf16x8 ap[2][2];
        ap[0][0] = *(const bf16x8*)&sP[(w * 32 + ln15) * 72 + pr0];
        ap[0][1] = *(const bf16x8*)&sP[(w * 32 + ln15) * 72 + pr1];
        ap[1][0] = *(const bf16x8*)&sP[(w * 32 + 16 + ln15) * 72 + pr0];
        ap[1][1] = *(const bf16x8*)&sP[(w * 32 + 16 + ln15) * 72 + pr1];
        #pragma unroll
        for (int t = 0; t < 5; t++) {
            bf16x8 bv0 = *(const bf16x8*)&sVT[(t * 16 + ln15) * 72 + quad * 8];
            bf16x8 bv1 = *(const bf16x8*)&sVT[(t * 16 + ln15) * 72 + 32 + quad * 8];
            #pragma unroll
            for (int rf = 0; rf < 2; rf++) {
                o[rf][t] = __builtin_amdgcn_mfma_f32_16x16x32_bf16(ap[rf][0], bv0, o[rf][t], 0, 0, 0);
                o[rf][t] = __builtin_amdgcn_mfma_f32_16x16x32_bf16(ap[rf][1], bv1, o[rf][t], 0, 0, 0);
            }
        }
    }

    // ---- store partials (unnormalized O and l; merge just sums)
    size_t kso = (size_t)ks * NROW;
    #pragma unroll
    for (int rf = 0; rf < 2; rf++) {
        #pragma unroll
        for (int reg = 0; reg < 4; reg++) {
            size_t row = (size_t)bh * MM + i0 + w * 32 + rf * 16 + quad * 4 + reg;
            unsigned short* orow = obuf + (kso + row) * 72;
            #pragma unroll
            for (int t = 0; t < 4; t++)
                orow[t * 16 + ln15] = f2bf_bits(o[rf][t][reg]);
            if (ln15 < 3)  orow[64 + ln15] = f2bf_bits(o[rf][4][reg]);   // xyz agg
            if (ln15 == 3) lbuf[kso + row] = o[rf][4][reg];              // l (fp32)
        }
    }
}

// ---------------- merge 4 split-K partials + w_sp epilogue -> bf16 ---------
__global__ __launch_bounds__(256) void merge_kernel(
    const unsigned short* __restrict__ obuf, const float* __restrict__ lbuf,
    const float* __restrict__ xyzs, const float* __restrict__ wsp,
    unsigned short* __restrict__ attn_out)
{
    __shared__ float sW[3][64];
    int tid = threadIdx.x;
    if (tid < 192) sW[tid >> 6][tid & 63] = wsp[tid];
    __syncthreads();
    int r   = blockIdx.x * 64 + (tid >> 2);
    int d0  = (tid & 3) * 16;
    int bh = r >> 11, qrow = r & 2047, bb = bh >> 3, hh = bh & 7;
    const unsigned short* p0 = obuf + (size_t)r * 72;
    const unsigned short* p1 = p0 + (size_t)NROW * 72;
    const unsigned short* p2 = p1 + (size_t)NROW * 72;
    const unsigned short* p3 = p2 + (size_t)NROW * 72;
    float invl = 1.f / (lbuf[r] + lbuf[NROW + r] + lbuf[2 * NROW + r] + lbuf[3 * NROW + r]);
    size_t xb = ((size_t)bb * MM + qrow) * 3;
    float gx = (bf2f(p0[64]) + bf2f(p1[64]) + bf2f(p2[64]) + bf2f(p3[64])) * invl - xyzs[xb + 0];
    float gy = (bf2f(p0[65]) + bf2f(p1[65]) + bf2f(p2[65]) + bf2f(p3[65])) * invl - xyzs[xb + 1];
    float gz = (bf2f(p0[66]) + bf2f(p1[66]) + bf2f(p2[66]) + bf2f(p3[66])) * invl - xyzs[xb + 2];
    us8 a0 = *(const us8*)&p0[d0];
    us8 a1 = *(const us8*)&p0[d0 + 8];
    us8 b0 = *(const us8*)&p1[d0];
    us8 b1 = *(const us8*)&p1[d0 + 8];
    us8 c0 = *(const us8*)&p2[d0];
    us8 c1 = *(const us8*)&p2[d0 + 8];
    us8 e0 = *(const us8*)&p3[d0];
    us8 e1 = *(const us8*)&p3[d0 + 8];
    unsigned short outv[16];
    #pragma unroll
    for (int e = 0; e < 8; e++) {
        int d = d0 + e;
        float v = (bf2f(a0[e]) + bf2f(b0[e]) + bf2f(c0[e]) + bf2f(e0[e])) * invl
                + gx * sW[0][d] + gy * sW[1][d] + gz * sW[2][d];
        outv[e] = f2bf_bits(v);
    }
    #pragma unroll
    for (int e = 0; e < 8; e++) {
        int d = d0 + 8 + e;
        float v = (bf2f(a1[e]) + bf2f(b1[e]) + bf2f(c1[e]) + bf2f(e1[e])) * invl
                + gx * sW[0][d] + gy * sW[1][d] + gz * sW[2][d];
        outv[8 + e] = f2bf_bits(v);
    }
    unsigned short* dst = attn_out + ((size_t)bb * MM + qrow) * DIM + hh * DHd + d0;
    *(us8*)dst       = *(us8*)&outv[0];
    *(us8*)(dst + 8) = *(us8*)&outv[8];
}

// ---- out GEMM (MFMA, 64x64 tiles for occupancy): bf16 A @ bf16 BT^T
//      + bias + exact GeLU + residual -> fp32
__global__ __launch_bounds__(256) void out_gemm(
    const unsigned short* __restrict__ A, const unsigned short* __restrict__ BT,
    const float* __restrict__ bias, const float* __restrict__ feat,
    float* __restrict__ out)
{
    __shared__ __align__(16) unsigned short sA[64 * 40];
    __shared__ __align__(16) unsigned short sB[64 * 40];
    int tid = threadIdx.x;
    int r0 = blockIdx.x * 64, n0 = blockIdx.y * 64;
    int w = tid >> 6, lane = tid & 63;
    int wm = w >> 1, wn = w & 1;
    int ln15 = lane & 15, quad = lane >> 4;

    int srow = tid >> 2, scol = (tid & 3) * 8;   // 64 rows x 4 chunks of 8

    f32x4 acc[2][2] = {};

    for (int k0 = 0; k0 < DIM; k0 += 32) {
        __syncthreads();
        *(us8*)&sA[srow * 40 + scol] = *(const us8*)&A[(size_t)(r0 + srow) * DIM + k0 + scol];
        *(us8*)&sB[srow * 40 + scol] = *(const us8*)&BT[(size_t)(n0 + srow) * DIM + k0 + scol];
        __syncthreads();
        bf16x8 af[2], bf_[2];
        #pragma unroll
        for (int i = 0; i < 2; i++)
            af[i] = *(const bf16x8*)&sA[(wm * 32 + i * 16 + ln15) * 40 + quad * 8];
        #pragma unroll
        for (int j = 0; j < 2; j++)
            bf_[j] = *(const bf16x8*)&sB[(wn * 32 + j * 16 + ln15) * 40 + quad * 8];
        #pragma unroll
        for (int i = 0; i < 2; i++)
            #pragma unroll
            for (int j = 0; j < 2; j++)
                acc[i][j] = __builtin_amdgcn_mfma_f32_16x16x32_bf16(af[i], bf_[j], acc[i][j], 0, 0, 0);
    }

    #pragma unroll
    for (int i = 0; i < 2; i++) {
        #pragma unroll
        for (int reg = 0; reg < 4; reg++) {
            int gr = r0 + wm * 32 + i * 16 + quad * 4 + reg;
            #pragma unroll
            for (int j = 0; j < 2; j++) {
                int c = n0 + wn * 32 + j * 16 + ln15;
                float x = acc[i][j][reg] + bias[c];
                float g = 0.5f * x * (1.f + erff(x * 0.70710678118f));
                out[(size_t)gr * DIM + c] = g + feat[(size_t)gr * DIM + c];
            }
        }
    }
}

extern "C" void kernel_launch(void* const* d_in, const int* in_sizes, int n_in,
                              void* d_out, int out_size, void* d_ws, size_t ws_size,
                              hipStream_t stream)
{
    const float* xyzs  = (const float*)d_in[0];
    const float* feat  = (const float*)d_in[1];
    const float* gamma = (const float*)d_in[2];
    const float* beta  = (const float*)d_in[3];
    const float* wqkv  = (const float*)d_in[4];
    const float* wsp   = (const float*)d_in[5];
    const float* wout  = (const float*)d_in[6];
    const float* bout  = (const float*)d_in[7];
    float* out = (float*)d_out;

    unsigned short* ws16 = (unsigned short*)d_ws;
    const size_t SEGS = (size_t)ROWS * DIM;              // 2,097,152 shorts (4 MB)
    unsigned short* normed = ws16;                       // reused as attn_out
    unsigned short* qb     = ws16 + SEGS;
    unsigned short* kb     = ws16 + 2 * SEGS;
    unsigned short* vb     = ws16 + 3 * SEGS;
    unsigned short* wqkvT  = ws16 + 4 * SEGS;            // 786,432 shorts
    unsigned short* woutT  = wqkvT + (size_t)NQK * DIM;  // 262,144 shorts
    unsigned short* obuf   = woutT + (size_t)DIM * DIM;  // 4*32768*72 shorts (18.9 MB)
    float*          lbuf   = (float*)(obuf + (size_t)SPLITK * NROW * 72); // 4*32768 f32

    pre_kernel<<<ROWS + 256, 256, 0, stream>>>(feat, gamma, beta, normed,
                                               wqkv, wout, wqkvT, woutT);
    qkv_gemm<<<dim3(32, 12), 256, 0, stream>>>(normed, wqkvT, qb, kb, vb);
    attn_kernel<<<dim3(16, 16, SPLITK), 256, 0, stream>>>(qb, kb, vb, xyzs, obuf, lbuf);
    merge_kernel<<<512, 256, 0, stream>>>(obuf, lbuf, xyzs, wsp, normed);
    out_gemm<<<dim3(64, 8), 256, 0, stream>>>(normed, woutT, bout, feat, out);
}

// Round 3
// 144.141 us; speedup vs baseline: 1.0691x; 1.0411x over previous
//
#include <hip/hip_runtime.h>
#include <hip/hip_bf16.h>
#include <math.h>

#define BB   2
#define MM   2048      // l*n
#define DIM  512
#define NH   8
#define DHd  64
#define NQK  1536
#define ROWS 4096      // BB*MM
#define NROW 32768     // 16 bh * 2048 rows (rows per split-K partial)
#define SPLITK 4

typedef __hip_bfloat16 bf16;
typedef __attribute__((ext_vector_type(8))) short bf16x8;
typedef __attribute__((ext_vector_type(4))) float f32x4;
typedef __attribute__((ext_vector_type(8))) unsigned short us8;

__device__ __forceinline__ unsigned short f2bf_bits(float x) {
    bf16 h = __float2bfloat16(x);
    return *(unsigned short*)&h;
}
__device__ __forceinline__ float bf2f(unsigned short u) {
    unsigned int v = ((unsigned int)u) << 16;
    return __uint_as_float(v);
}

// ---- fused pre-pass: LayerNorm (wave-per-row, blocks 0..1023) + transposes
__global__ __launch_bounds__(256) void pre_kernel(
    const float* __restrict__ feat, const float* __restrict__ gamma,
    const float* __restrict__ beta, unsigned short* __restrict__ normed,
    const float* __restrict__ wqkv, const float* __restrict__ wout,
    unsigned short* __restrict__ wqkvT, unsigned short* __restrict__ woutT)
{
    __shared__ float st[64][65];
    int b = blockIdx.x;
    int tid = threadIdx.x;
    if (b < ROWS / 4) {
        // ---- LayerNorm: one wave per row, 8 elems/lane, no barriers
        int w = tid >> 6, lane = tid & 63;
        int row = b * 4 + w;
        const float* fr = feat + (size_t)row * DIM + lane * 8;
        float4 v0 = *(const float4*)fr;
        float4 v1 = *(const float4*)(fr + 4);
        float s  = v0.x + v0.y + v0.z + v0.w + v1.x + v1.y + v1.z + v1.w;
        float ss = v0.x*v0.x + v0.y*v0.y + v0.z*v0.z + v0.w*v0.w
                 + v1.x*v1.x + v1.y*v1.y + v1.z*v1.z + v1.w*v1.w;
        #pragma unroll
        for (int o = 32; o >= 1; o >>= 1) { s += __shfl_xor(s, o); ss += __shfl_xor(ss, o); }
        float mu  = s * (1.0f / DIM);
        float var = ss * (1.0f / DIM) - mu * mu;
        float inv = rsqrtf(var + 1e-5f);
        const float* gp = gamma + lane * 8;
        const float* bp = beta  + lane * 8;
        float4 g0 = *(const float4*)gp, g1 = *(const float4*)(gp + 4);
        float4 e0 = *(const float4*)bp, e1 = *(const float4*)(bp + 4);
        unsigned short ov[8];
        ov[0] = f2bf_bits((v0.x - mu) * inv * g0.x + e0.x);
        ov[1] = f2bf_bits((v0.y - mu) * inv * g0.y + e0.y);
        ov[2] = f2bf_bits((v0.z - mu) * inv * g0.z + e0.z);
        ov[3] = f2bf_bits((v0.w - mu) * inv * g0.w + e0.w);
        ov[4] = f2bf_bits((v1.x - mu) * inv * g1.x + e1.x);
        ov[5] = f2bf_bits((v1.y - mu) * inv * g1.y + e1.y);
        ov[6] = f2bf_bits((v1.z - mu) * inv * g1.z + e1.z);
        ov[7] = f2bf_bits((v1.w - mu) * inv * g1.w + e1.w);
        *(us8*)&normed[(size_t)row * DIM + lane * 8] = *(us8*)ov;
        return;
    }
    // ---- weight transpose: out[n][k] = bf16(in[k][n])
    int idx = b - ROWS / 4;
    const float* in; unsigned short* out; int N, n0;
    if (idx < 192) { in = wqkv; out = wqkvT; N = NQK; n0 = (idx >> 3) * 64; }
    else { idx -= 192; in = wout; out = woutT; N = DIM; n0 = (idx >> 3) * 64; }
    int k0 = (idx & 7) * 64;
    #pragma unroll
    for (int p = 0; p < 16; p++) {
        int e = tid + p * 256;
        int r = e >> 6, c = e & 63;
        st[r][c] = in[(size_t)(k0 + r) * N + n0 + c];
    }
    __syncthreads();
    #pragma unroll
    for (int p = 0; p < 16; p++) {
        int e = tid + p * 256;
        int nr = e >> 6, kc = e & 63;
        out[(size_t)(n0 + nr) * DIM + k0 + kc] = f2bf_bits(st[kc][nr]);
    }
}

// ---- QKV GEMM v3: 128x64 tiles, grid 768 = exactly 3 blocks/CU, BK=64,
//      register prefetch. q/k computed transposed (weights as first operand)
//      so the accumulator reg axis lands on d -> ushort4 stores.
__global__ __launch_bounds__(256) void qkv_gemm(
    const unsigned short* __restrict__ A, const unsigned short* __restrict__ BT,
    unsigned short* __restrict__ qd, unsigned short* __restrict__ kd,
    unsigned short* __restrict__ vd)
{
    __shared__ __align__(16) unsigned short sA[128 * 72];
    __shared__ __align__(16) unsigned short sB[64 * 72];
    int tid = threadIdx.x;
    int r0 = blockIdx.x * 128;          // normed rows
    int n0 = blockIdx.y * 64;           // qkv cols
    int chunk = n0 >> 9;                // 0=q 1=k 2=v
    int h     = (n0 & 511) >> 6;        // head index (64-col slice)
    int w = tid >> 6, lane = tid & 63;
    int wm = w >> 1, wn = w & 1;        // wave tile: 64m x 32n
    int ln15 = lane & 15, quad = lane >> 4;

    int arow = tid >> 1, acol = (tid & 1) * 32;   // A stage: 128 x 64
    int brow = tid >> 2, bcol = (tid & 3) * 16;   // B stage: 64 x 64

    f32x4 acc[4][2] = {};
    us8 ra[4], rb[2];

    #pragma unroll
    for (int u = 0; u < 4; u++)
        ra[u] = *(const us8*)&A[(size_t)(r0 + arow) * DIM + acol + u * 8];
    #pragma unroll
    for (int u = 0; u < 2; u++)
        rb[u] = *(const us8*)&BT[(size_t)(n0 + brow) * DIM + bcol + u * 8];

    for (int k0 = 0; k0 < DIM; k0 += 64) {
        __syncthreads();
        #pragma unroll
        for (int u = 0; u < 4; u++) *(us8*)&sA[arow * 72 + acol + u * 8] = ra[u];
        #pragma unroll
        for (int u = 0; u < 2; u++) *(us8*)&sB[brow * 72 + bcol + u * 8] = rb[u];
        __syncthreads();
        int kn = k0 + 64;
        if (kn < DIM) {
            #pragma unroll
            for (int u = 0; u < 4; u++)
                ra[u] = *(const us8*)&A[(size_t)(r0 + arow) * DIM + kn + acol + u * 8];
            #pragma unroll
            for (int u = 0; u < 2; u++)
                rb[u] = *(const us8*)&BT[(size_t)(n0 + brow) * DIM + kn + bcol + u * 8];
        }
        bf16x8 fa[4][2], fb[2][2];
        #pragma unroll
        for (int i = 0; i < 4; i++)
            #pragma unroll
            for (int kk = 0; kk < 2; kk++)
                fa[i][kk] = *(const bf16x8*)&sA[(wm * 64 + i * 16 + ln15) * 72 + kk * 32 + quad * 8];
        #pragma unroll
        for (int j = 0; j < 2; j++)
            #pragma unroll
            for (int kk = 0; kk < 2; kk++)
                fb[j][kk] = *(const bf16x8*)&sB[(wn * 32 + j * 16 + ln15) * 72 + kk * 32 + quad * 8];
        if (chunk == 2) {
            #pragma unroll
            for (int kk = 0; kk < 2; kk++)
                #pragma unroll
                for (int i = 0; i < 4; i++)
                    #pragma unroll
                    for (int j = 0; j < 2; j++)
                        acc[i][j] = __builtin_amdgcn_mfma_f32_16x16x32_bf16(fa[i][kk], fb[j][kk], acc[i][j], 0, 0, 0);
        } else {
            #pragma unroll
            for (int kk = 0; kk < 2; kk++)
                #pragma unroll
                for (int i = 0; i < 4; i++)
                    #pragma unroll
                    for (int j = 0; j < 2; j++)
                        acc[i][j] = __builtin_amdgcn_mfma_f32_16x16x32_bf16(fb[j][kk], fa[i][kk], acc[i][j], 0, 0, 0);
        }
    }

    if (chunk == 2) {
        // D[m][n]: reg axis on m -> ushort4 along m in [bh][d][m] layout
        #pragma unroll
        for (int i = 0; i < 4; i++) {
            int gm = r0 + wm * 64 + i * 16 + quad * 4;
            int bb = gm >> 11, mm = gm & 2047;
            #pragma unroll
            for (int j = 0; j < 2; j++) {
                int d = wn * 32 + j * 16 + ln15;
                ushort4 pk;
                pk.x = f2bf_bits(acc[i][j][0]);
                pk.y = f2bf_bits(acc[i][j][1]);
                pk.z = f2bf_bits(acc[i][j][2]);
                pk.w = f2bf_bits(acc[i][j][3]);
                *(ushort4*)&vd[((size_t)(bb * NH + h) * DHd + d) * MM + mm] = pk;
            }
        }
    } else {
        // D[n][m]: reg axis on d -> ushort4 along d in [bh][m][d] layout
        unsigned short* dst = (chunk == 0) ? qd : kd;
        float sc = (chunk == 0) ? 0.125f : 1.0f;
        #pragma unroll
        for (int i = 0; i < 4; i++) {
            int gm = r0 + wm * 64 + i * 16 + ln15;
            int bb = gm >> 11, mm = gm & 2047;
            #pragma unroll
            for (int j = 0; j < 2; j++) {
                int d0 = wn * 32 + j * 16 + quad * 4;
                ushort4 pk;
                pk.x = f2bf_bits(acc[i][j][0] * sc);
                pk.y = f2bf_bits(acc[i][j][1] * sc);
                pk.z = f2bf_bits(acc[i][j][2] * sc);
                pk.w = f2bf_bits(acc[i][j][3] * sc);
                *(ushort4*)&dst[((size_t)(bb * NH + h) * MM + mm) * DHd + d0] = pk;
            }
        }
    }
}

// ---------------- MFMA flash attention v2 ----------------------------------
// 32 Q-rows per wave (2 row-frags) -> K/V fragment reads amortized 2x.
// Q fragments loaded directly from global (no sQ). Split-K = 4 keeps the
// grid at 1024 blocks (4 blocks/CU, 16 waves/CU; LDS 39.2KB -> 4 blocks).
// No online max (S bounded by construction; shift-invariant softmax, m=0).
// V extended: cols 64..66 = key xyz, col 67 = 1.0 (gives l), 68..79 = 0.
// K/V/xyz for tile j+1 prefetched into VGPRs during tile j's compute.
__global__ __launch_bounds__(256, 4) void attn_kernel(
    const unsigned short* __restrict__ qg, const unsigned short* __restrict__ kg,
    const unsigned short* __restrict__ vg, const float* __restrict__ xyzs,
    unsigned short* __restrict__ obuf, float* __restrict__ lbuf)
{
    __shared__ __align__(16) unsigned short sK[64 * 72];
    __shared__ __align__(16) unsigned short sVT[80 * 72];
    __shared__ __align__(16) unsigned short sP[128 * 72];

    int tid = threadIdx.x;
    int bh = blockIdx.y; int bb = bh >> 3;
    int i0 = blockIdx.x * 128;
    int ks = blockIdx.z;
    int w = tid >> 6;
    int lane = tid & 63;
    int ln15 = lane & 15;
    int quad = lane >> 4;

    // one-time inits: zero pad rows 68..79, ones row 67
    for (int e = tid; e < 12 * 72; e += 256) sVT[68 * 72 + e] = 0;
    if (tid < 64) sVT[67 * 72 + tid] = 0x3F80;   // bf16 1.0

    // Q fragments direct from global (row-major [row][d] matches A-frag)
    bf16x8 aq[2][2];
    {
        const unsigned short* q0 = qg + ((size_t)bh * MM + i0 + w * 32 + ln15) * DHd + quad * 8;
        aq[0][0] = *(const bf16x8*)q0;
        aq[0][1] = *(const bf16x8*)(q0 + 32);
        aq[1][0] = *(const bf16x8*)(q0 + 16 * DHd);
        aq[1][1] = *(const bf16x8*)(q0 + 16 * DHd + 32);
    }

    f32x4 o[2][5] = {};   // t=0..3: V cols; t=4: [x,y,z,l] at ln15=0..3

    const unsigned short* kbase = kg + (size_t)bh * MM * DHd;
    const unsigned short* vbase = vg + (size_t)bh * DHd * MM;
    int jbeg = ks * (MM / SPLITK), jend = jbeg + (MM / SPLITK);

    int srow = tid >> 2, scol16 = (tid & 3) * 16;   // staging coords (K and VT)

    us8 rk0, rk1, rv0, rv1;
    float rx = 0.f;
    {   // preload first tile
        const unsigned short* src = kbase + (size_t)jbeg * DHd;
        rk0 = *(const us8*)&src[(size_t)tid * 16];
        rk1 = *(const us8*)&src[(size_t)tid * 16 + 8];
        const unsigned short* vs = vbase + jbeg;
        rv0 = *(const us8*)&vs[(size_t)srow * MM + scol16];
        rv1 = *(const us8*)&vs[(size_t)srow * MM + scol16 + 8];
        if (tid < 192) rx = xyzs[((size_t)bb * MM + jbeg) * 3 + tid];
    }

    int pwb = quad << 4;                       // write-side swizzle for sP
    int swzr = (ln15 >> 2) << 4;               // read-side swizzle
    int pr0 = (quad * 8) ^ swzr;
    int pr1 = (32 + quad * 8) ^ swzr;

    for (int jt = jbeg; jt < jend; jt += 64) {
        __syncthreads();
        // commit prefetched tile to LDS
        *(us8*)&sK[srow * 72 + scol16]      = rk0;
        *(us8*)&sK[srow * 72 + scol16 + 8]  = rk1;
        *(us8*)&sVT[srow * 72 + scol16]     = rv0;
        *(us8*)&sVT[srow * 72 + scol16 + 8] = rv1;
        if (tid < 192) {
            int key = tid / 3, c = tid - key * 3;
            sVT[(64 + c) * 72 + key] = f2bf_bits(rx);
        }
        __syncthreads();
        // issue prefetch for next tile (consumed next iteration)
        int jn = jt + 64;
        if (jn < jend) {
            const unsigned short* src = kbase + (size_t)jn * DHd;
            rk0 = *(const us8*)&src[(size_t)tid * 16];
            rk1 = *(const us8*)&src[(size_t)tid * 16 + 8];
            const unsigned short* vs = vbase + jn;
            rv0 = *(const us8*)&vs[(size_t)srow * MM + scol16];
            rv1 = *(const us8*)&vs[(size_t)srow * MM + scol16 + 8];
            if (tid < 192) rx = xyzs[((size_t)bb * MM + jn) * 3 + tid];
        }

        // QK^T: K fragments loaded once per t, reused for both row-frags.
        // exp + packed-bf16 P write fused per (t, rf) so S never persists.
        #pragma unroll
        for (int t = 0; t < 4; t++) {
            bf16x8 bk0 = *(const bf16x8*)&sK[(t * 16 + ln15) * 72 + quad * 8];
            bf16x8 bk1 = *(const bf16x8*)&sK[(t * 16 + ln15) * 72 + 32 + quad * 8];
            int colb = (t * 16) ^ pwb;
            #pragma unroll
            for (int rf = 0; rf < 2; rf++) {
                f32x4 z = {};
                z = __builtin_amdgcn_mfma_f32_16x16x32_bf16(aq[rf][0], bk0, z, 0, 0, 0);
                z = __builtin_amdgcn_mfma_f32_16x16x32_bf16(aq[rf][1], bk1, z, 0, 0, 0);
                int rbase = (w * 32 + rf * 16 + quad * 4) * 72 + colb + ln15;
                sP[rbase]           = f2bf_bits(__expf(z[0]));
                sP[rbase + 72]      = f2bf_bits(__expf(z[1]));
                sP[rbase + 144]     = f2bf_bits(__expf(z[2]));
                sP[rbase + 216]     = f2bf_bits(__expf(z[3]));
            }
        }
        asm volatile("s_waitcnt lgkmcnt(0)" ::: "memory");
        bf16x8 ap[2][2];
        ap[0][0] = *(const bf16x8*)&sP[(w * 32 + ln15) * 72 + pr0];
        ap[0][1] = *(const bf16x8*)&sP[(w * 32 + ln15) * 72 + pr1];
        ap[1][0] = *(const bf16x8*)&sP[(w * 32 + 16 + ln15) * 72 + pr0];
        ap[1][1] = *(const bf16x8*)&sP[(w * 32 + 16 + ln15) * 72 + pr1];
        #pragma unroll
        for (int t = 0; t < 5; t++) {
            bf16x8 bv0 = *(const bf16x8*)&sVT[(t * 16 + ln15) * 72 + quad * 8];
            bf16x8 bv1 = *(const bf16x8*)&sVT[(t * 16 + ln15) * 72 + 32 + quad * 8];
            #pragma unroll
            for (int rf = 0; rf < 2; rf++) {
                o[rf][t] = __builtin_amdgcn_mfma_f32_16x16x32_bf16(ap[rf][0], bv0, o[rf][t], 0, 0, 0);
                o[rf][t] = __builtin_amdgcn_mfma_f32_16x16x32_bf16(ap[rf][1], bv1, o[rf][t], 0, 0, 0);
            }
        }
    }

    // ---- store partials (unnormalized O and l; merge just sums)
    size_t kso = (size_t)ks * NROW;
    #pragma unroll
    for (int rf = 0; rf < 2; rf++) {
        #pragma unroll
        for (int reg = 0; reg < 4; reg++) {
            size_t row = (size_t)bh * MM + i0 + w * 32 + rf * 16 + quad * 4 + reg;
            unsigned short* orow = obuf + (kso + row) * 72;
            #pragma unroll
            for (int t = 0; t < 4; t++)
                orow[t * 16 + ln15] = f2bf_bits(o[rf][t][reg]);
            if (ln15 < 3)  orow[64 + ln15] = f2bf_bits(o[rf][4][reg]);   // xyz agg
            if (ln15 == 3) lbuf[kso + row] = o[rf][4][reg];              // l (fp32)
        }
    }
}

// ---------------- merge 4 split-K partials + w_sp epilogue -> bf16 ---------
__global__ __launch_bounds__(256) void merge_kernel(
    const unsigned short* __restrict__ obuf, const float* __restrict__ lbuf,
    const float* __restrict__ xyzs, const float* __restrict__ wsp,
    unsigned short* __restrict__ attn_out)
{
    __shared__ float sW[3][64];
    int tid = threadIdx.x;
    if (tid < 192) sW[tid >> 6][tid & 63] = wsp[tid];
    __syncthreads();
    int r   = blockIdx.x * 64 + (tid >> 2);
    int d0  = (tid & 3) * 16;
    int bh = r >> 11, qrow = r & 2047, bb = bh >> 3, hh = bh & 7;
    const unsigned short* p0 = obuf + (size_t)r * 72;
    const unsigned short* p1 = p0 + (size_t)NROW * 72;
    const unsigned short* p2 = p1 + (size_t)NROW * 72;
    const unsigned short* p3 = p2 + (size_t)NROW * 72;
    float invl = 1.f / (lbuf[r] + lbuf[NROW + r] + lbuf[2 * NROW + r] + lbuf[3 * NROW + r]);
    size_t xb = ((size_t)bb * MM + qrow) * 3;
    float gx = (bf2f(p0[64]) + bf2f(p1[64]) + bf2f(p2[64]) + bf2f(p3[64])) * invl - xyzs[xb + 0];
    float gy = (bf2f(p0[65]) + bf2f(p1[65]) + bf2f(p2[65]) + bf2f(p3[65])) * invl - xyzs[xb + 1];
    float gz = (bf2f(p0[66]) + bf2f(p1[66]) + bf2f(p2[66]) + bf2f(p3[66])) * invl - xyzs[xb + 2];
    us8 a0 = *(const us8*)&p0[d0];
    us8 a1 = *(const us8*)&p0[d0 + 8];
    us8 b0 = *(const us8*)&p1[d0];
    us8 b1 = *(const us8*)&p1[d0 + 8];
    us8 c0 = *(const us8*)&p2[d0];
    us8 c1 = *(const us8*)&p2[d0 + 8];
    us8 e0 = *(const us8*)&p3[d0];
    us8 e1 = *(const us8*)&p3[d0 + 8];
    unsigned short outv[16];
    #pragma unroll
    for (int e = 0; e < 8; e++) {
        int d = d0 + e;
        float v = (bf2f(a0[e]) + bf2f(b0[e]) + bf2f(c0[e]) + bf2f(e0[e])) * invl
                + gx * sW[0][d] + gy * sW[1][d] + gz * sW[2][d];
        outv[e] = f2bf_bits(v);
    }
    #pragma unroll
    for (int e = 0; e < 8; e++) {
        int d = d0 + 8 + e;
        float v = (bf2f(a1[e]) + bf2f(b1[e]) + bf2f(c1[e]) + bf2f(e1[e])) * invl
                + gx * sW[0][d] + gy * sW[1][d] + gz * sW[2][d];
        outv[8 + e] = f2bf_bits(v);
    }
    unsigned short* dst = attn_out + ((size_t)bb * MM + qrow) * DIM + hh * DHd + d0;
    *(us8*)dst       = *(us8*)&outv[0];
    *(us8*)(dst + 8) = *(us8*)&outv[8];
}

// ---- out GEMM v2: 64x64 tiles, BK=64, register prefetch
//      bf16 A @ bf16 BT^T + bias + exact GeLU + residual -> fp32
__global__ __launch_bounds__(256) void out_gemm(
    const unsigned short* __restrict__ A, const unsigned short* __restrict__ BT,
    const float* __restrict__ bias, const float* __restrict__ feat,
    float* __restrict__ out)
{
    __shared__ __align__(16) unsigned short sA[64 * 72];
    __shared__ __align__(16) unsigned short sB[64 * 72];
    int tid = threadIdx.x;
    int r0 = blockIdx.x * 64, n0 = blockIdx.y * 64;
    int w = tid >> 6, lane = tid & 63;
    int wm = w >> 1, wn = w & 1;
    int ln15 = lane & 15, quad = lane >> 4;

    int srow = tid >> 2, scol = (tid & 3) * 16;   // 64 rows x 64 cols stage

    f32x4 acc[2][2] = {};
    us8 ra[2], rb[2];

    #pragma unroll
    for (int u = 0; u < 2; u++) {
        ra[u] = *(const us8*)&A[(size_t)(r0 + srow) * DIM + scol + u * 8];
        rb[u] = *(const us8*)&BT[(size_t)(n0 + srow) * DIM + scol + u * 8];
    }

    for (int k0 = 0; k0 < DIM; k0 += 64) {
        __syncthreads();
        #pragma unroll
        for (int u = 0; u < 2; u++) {
            *(us8*)&sA[srow * 72 + scol + u * 8] = ra[u];
            *(us8*)&sB[srow * 72 + scol + u * 8] = rb[u];
        }
        __syncthreads();
        int kn = k0 + 64;
        if (kn < DIM) {
            #pragma unroll
            for (int u = 0; u < 2; u++) {
                ra[u] = *(const us8*)&A[(size_t)(r0 + srow) * DIM + kn + scol + u * 8];
                rb[u] = *(const us8*)&BT[(size_t)(n0 + srow) * DIM + kn + scol + u * 8];
            }
        }
        bf16x8 af[2][2], bf_[2][2];
        #pragma unroll
        for (int i = 0; i < 2; i++)
            #pragma unroll
            for (int kk = 0; kk < 2; kk++)
                af[i][kk] = *(const bf16x8*)&sA[(wm * 32 + i * 16 + ln15) * 72 + kk * 32 + quad * 8];
        #pragma unroll
        for (int j = 0; j < 2; j++)
            #pragma unroll
            for (int kk = 0; kk < 2; kk++)
                bf_[j][kk] = *(const bf16x8*)&sB[(wn * 32 + j * 16 + ln15) * 72 + kk * 32 + quad * 8];
        #pragma unroll
        for (int kk = 0; kk < 2; kk++)
            #pragma unroll
            for (int i = 0; i < 2; i++)
                #pragma unroll
                for (int j = 0; j < 2; j++)
                    acc[i][j] = __builtin_amdgcn_mfma_f32_16x16x32_bf16(af[i][kk], bf_[j][kk], acc[i][j], 0, 0, 0);
    }

    #pragma unroll
    for (int i = 0; i < 2; i++) {
        #pragma unroll
        for (int reg = 0; reg < 4; reg++) {
            int gr = r0 + wm * 32 + i * 16 + quad * 4 + reg;
            #pragma unroll
            for (int j = 0; j < 2; j++) {
                int c = n0 + wn * 32 + j * 16 + ln15;
                float x = acc[i][j][reg] + bias[c];
                float g = 0.5f * x * (1.f + erff(x * 0.70710678118f));
                out[(size_t)gr * DIM + c] = g + feat[(size_t)gr * DIM + c];
            }
        }
    }
}

extern "C" void kernel_launch(void* const* d_in, const int* in_sizes, int n_in,
                              void* d_out, int out_size, void* d_ws, size_t ws_size,
                              hipStream_t stream)
{
    const float* xyzs  = (const float*)d_in[0];
    const float* feat  = (const float*)d_in[1];
    const float* gamma = (const float*)d_in[2];
    const float* beta  = (const float*)d_in[3];
    const float* wqkv  = (const float*)d_in[4];
    const float* wsp   = (const float*)d_in[5];
    const float* wout  = (const float*)d_in[6];
    const float* bout  = (const float*)d_in[7];
    float* out = (float*)d_out;

    unsigned short* ws16 = (unsigned short*)d_ws;
    const size_t SEGS = (size_t)ROWS * DIM;              // 2,097,152 shorts (4 MB)
    unsigned short* normed = ws16;                       // reused as attn_out
    unsigned short* qb     = ws16 + SEGS;
    unsigned short* kb     = ws16 + 2 * SEGS;
    unsigned short* vb     = ws16 + 3 * SEGS;
    unsigned short* wqkvT  = ws16 + 4 * SEGS;            // 786,432 shorts
    unsigned short* woutT  = wqkvT + (size_t)NQK * DIM;  // 262,144 shorts
    unsigned short* obuf   = woutT + (size_t)DIM * DIM;  // 4*32768*72 shorts (18.9 MB)
    float*          lbuf   = (float*)(obuf + (size_t)SPLITK * NROW * 72); // 4*32768 f32

    pre_kernel<<<ROWS / 4 + 256, 256, 0, stream>>>(feat, gamma, beta, normed,
                                                   wqkv, wout, wqkvT, woutT);
    qkv_gemm<<<dim3(32, 24), 256, 0, stream>>>(normed, wqkvT, qb, kb, vb);
    attn_kernel<<<dim3(16, 16, SPLITK), 256, 0, stream>>>(qb, kb, vb, xyzs, obuf, lbuf);
    merge_kernel<<<512, 256, 0, stream>>>(obuf, lbuf, xyzs, wsp, normed);
    out_gemm<<<dim3(64, 8), 256, 0, stream>>>(normed, woutT, bout, feat, out);
}

// Round 4
// 141.790 us; speedup vs baseline: 1.0868x; 1.0166x over previous
//
#include <hip/hip_runtime.h>
#include <hip/hip_bf16.h>
#include <math.h>

#define BB   2
#define MM   2048      // l*n
#define DIM  512
#define NH   8
#define DHd  64
#define NQK  1536
#define ROWS 4096      // BB*MM
#define NROW 32768     // 16 bh * 2048 rows (rows per split-K partial)
#define SPLITK 3

typedef __hip_bfloat16 bf16;
typedef __attribute__((ext_vector_type(8))) short bf16x8;
typedef __attribute__((ext_vector_type(4))) float f32x4;
typedef __attribute__((ext_vector_type(16))) float f32x16;
typedef __attribute__((ext_vector_type(8))) unsigned short us8;
typedef __attribute__((ext_vector_type(4))) unsigned int u32x4;

__device__ __forceinline__ unsigned short f2bf_bits(float x) {
    bf16 h = __float2bfloat16(x);
    return *(unsigned short*)&h;
}
__device__ __forceinline__ float bf2f(unsigned short u) {
    unsigned int v = ((unsigned int)u) << 16;
    return __uint_as_float(v);
}
__device__ __forceinline__ unsigned cvtpk_bf16(float lo, float hi) {
    unsigned r;
    asm("v_cvt_pk_bf16_f32 %0, %1, %2" : "=v"(r) : "v"(lo), "v"(hi));
    return r;
}
__device__ __forceinline__ void pl32swap(unsigned &a, unsigned &b) {
    asm volatile("v_permlane32_swap_b32 %0, %1" : "+v"(a), "+v"(b));
}

// ---- fused pre-pass: LayerNorm (wave-per-row, blocks 0..1023) + transposes
__global__ __launch_bounds__(256) void pre_kernel(
    const float* __restrict__ feat, const float* __restrict__ gamma,
    const float* __restrict__ beta, unsigned short* __restrict__ normed,
    const float* __restrict__ wqkv, const float* __restrict__ wout,
    unsigned short* __restrict__ wqkvT, unsigned short* __restrict__ woutT)
{
    __shared__ float st[64][65];
    int b = blockIdx.x;
    int tid = threadIdx.x;
    if (b < ROWS / 4) {
        // ---- LayerNorm: one wave per row, 8 elems/lane, no barriers
        int w = tid >> 6, lane = tid & 63;
        int row = b * 4 + w;
        const float* fr = feat + (size_t)row * DIM + lane * 8;
        float4 v0 = *(const float4*)fr;
        float4 v1 = *(const float4*)(fr + 4);
        float s  = v0.x + v0.y + v0.z + v0.w + v1.x + v1.y + v1.z + v1.w;
        float ss = v0.x*v0.x + v0.y*v0.y + v0.z*v0.z + v0.w*v0.w
                 + v1.x*v1.x + v1.y*v1.y + v1.z*v1.z + v1.w*v1.w;
        #pragma unroll
        for (int o = 32; o >= 1; o >>= 1) { s += __shfl_xor(s, o); ss += __shfl_xor(ss, o); }
        float mu  = s * (1.0f / DIM);
        float var = ss * (1.0f / DIM) - mu * mu;
        float inv = rsqrtf(var + 1e-5f);
        const float* gp = gamma + lane * 8;
        const float* bp = beta  + lane * 8;
        float4 g0 = *(const float4*)gp, g1 = *(const float4*)(gp + 4);
        float4 e0 = *(const float4*)bp, e1 = *(const float4*)(bp + 4);
        unsigned short ov[8];
        ov[0] = f2bf_bits((v0.x - mu) * inv * g0.x + e0.x);
        ov[1] = f2bf_bits((v0.y - mu) * inv * g0.y + e0.y);
        ov[2] = f2bf_bits((v0.z - mu) * inv * g0.z + e0.z);
        ov[3] = f2bf_bits((v0.w - mu) * inv * g0.w + e0.w);
        ov[4] = f2bf_bits((v1.x - mu) * inv * g1.x + e1.x);
        ov[5] = f2bf_bits((v1.y - mu) * inv * g1.y + e1.y);
        ov[6] = f2bf_bits((v1.z - mu) * inv * g1.z + e1.z);
        ov[7] = f2bf_bits((v1.w - mu) * inv * g1.w + e1.w);
        *(us8*)&normed[(size_t)row * DIM + lane * 8] = *(us8*)ov;
        return;
    }
    // ---- weight transpose: out[n][k] = bf16(in[k][n])
    int idx = b - ROWS / 4;
    const float* in; unsigned short* out; int N, n0;
    if (idx < 192) { in = wqkv; out = wqkvT; N = NQK; n0 = (idx >> 3) * 64; }
    else { idx -= 192; in = wout; out = woutT; N = DIM; n0 = (idx >> 3) * 64; }
    int k0 = (idx & 7) * 64;
    #pragma unroll
    for (int p = 0; p < 16; p++) {
        int e = tid + p * 256;
        int r = e >> 6, c = e & 63;
        st[r][c] = in[(size_t)(k0 + r) * N + n0 + c];
    }
    __syncthreads();
    #pragma unroll
    for (int p = 0; p < 16; p++) {
        int e = tid + p * 256;
        int nr = e >> 6, kc = e & 63;
        out[(size_t)(n0 + nr) * DIM + k0 + kc] = f2bf_bits(st[kc][nr]);
    }
}

// ---- QKV GEMM v3: 128x64 tiles, grid 768 = exactly 3 blocks/CU, BK=64,
//      register prefetch. q/k computed transposed (weights as first operand)
//      so the accumulator reg axis lands on d -> ushort4 stores.
__global__ __launch_bounds__(256) void qkv_gemm(
    const unsigned short* __restrict__ A, const unsigned short* __restrict__ BT,
    unsigned short* __restrict__ qd, unsigned short* __restrict__ kd,
    unsigned short* __restrict__ vd)
{
    __shared__ __align__(16) unsigned short sA[128 * 72];
    __shared__ __align__(16) unsigned short sB[64 * 72];
    int tid = threadIdx.x;
    int r0 = blockIdx.x * 128;          // normed rows
    int n0 = blockIdx.y * 64;           // qkv cols
    int chunk = n0 >> 9;                // 0=q 1=k 2=v
    int h     = (n0 & 511) >> 6;        // head index (64-col slice)
    int w = tid >> 6, lane = tid & 63;
    int wm = w >> 1, wn = w & 1;        // wave tile: 64m x 32n
    int ln15 = lane & 15, quad = lane >> 4;

    int arow = tid >> 1, acol = (tid & 1) * 32;   // A stage: 128 x 64
    int brow = tid >> 2, bcol = (tid & 3) * 16;   // B stage: 64 x 64

    f32x4 acc[4][2] = {};
    us8 ra[4], rb[2];

    #pragma unroll
    for (int u = 0; u < 4; u++)
        ra[u] = *(const us8*)&A[(size_t)(r0 + arow) * DIM + acol + u * 8];
    #pragma unroll
    for (int u = 0; u < 2; u++)
        rb[u] = *(const us8*)&BT[(size_t)(n0 + brow) * DIM + bcol + u * 8];

    for (int k0 = 0; k0 < DIM; k0 += 64) {
        __syncthreads();
        #pragma unroll
        for (int u = 0; u < 4; u++) *(us8*)&sA[arow * 72 + acol + u * 8] = ra[u];
        #pragma unroll
        for (int u = 0; u < 2; u++) *(us8*)&sB[brow * 72 + bcol + u * 8] = rb[u];
        __syncthreads();
        int kn = k0 + 64;
        if (kn < DIM) {
            #pragma unroll
            for (int u = 0; u < 4; u++)
                ra[u] = *(const us8*)&A[(size_t)(r0 + arow) * DIM + kn + acol + u * 8];
            #pragma unroll
            for (int u = 0; u < 2; u++)
                rb[u] = *(const us8*)&BT[(size_t)(n0 + brow) * DIM + kn + bcol + u * 8];
        }
        bf16x8 fa[4][2], fb[2][2];
        #pragma unroll
        for (int i = 0; i < 4; i++)
            #pragma unroll
            for (int kk = 0; kk < 2; kk++)
                fa[i][kk] = *(const bf16x8*)&sA[(wm * 64 + i * 16 + ln15) * 72 + kk * 32 + quad * 8];
        #pragma unroll
        for (int j = 0; j < 2; j++)
            #pragma unroll
            for (int kk = 0; kk < 2; kk++)
                fb[j][kk] = *(const bf16x8*)&sB[(wn * 32 + j * 16 + ln15) * 72 + kk * 32 + quad * 8];
        if (chunk == 2) {
            #pragma unroll
            for (int kk = 0; kk < 2; kk++)
                #pragma unroll
                for (int i = 0; i < 4; i++)
                    #pragma unroll
                    for (int j = 0; j < 2; j++)
                        acc[i][j] = __builtin_amdgcn_mfma_f32_16x16x32_bf16(fa[i][kk], fb[j][kk], acc[i][j], 0, 0, 0);
        } else {
            #pragma unroll
            for (int kk = 0; kk < 2; kk++)
                #pragma unroll
                for (int i = 0; i < 4; i++)
                    #pragma unroll
                    for (int j = 0; j < 2; j++)
                        acc[i][j] = __builtin_amdgcn_mfma_f32_16x16x32_bf16(fb[j][kk], fa[i][kk], acc[i][j], 0, 0, 0);
        }
    }

    if (chunk == 2) {
        // D[m][n]: reg axis on m -> ushort4 along m in [bh][d][m] layout
        #pragma unroll
        for (int i = 0; i < 4; i++) {
            int gm = r0 + wm * 64 + i * 16 + quad * 4;
            int bb = gm >> 11, mm = gm & 2047;
            #pragma unroll
            for (int j = 0; j < 2; j++) {
                int d = wn * 32 + j * 16 + ln15;
                ushort4 pk;
                pk.x = f2bf_bits(acc[i][j][0]);
                pk.y = f2bf_bits(acc[i][j][1]);
                pk.z = f2bf_bits(acc[i][j][2]);
                pk.w = f2bf_bits(acc[i][j][3]);
                *(ushort4*)&vd[((size_t)(bb * NH + h) * DHd + d) * MM + mm] = pk;
            }
        }
    } else {
        // D[n][m]: reg axis on d -> ushort4 along d in [bh][m][d] layout
        unsigned short* dst = (chunk == 0) ? qd : kd;
        float sc = (chunk == 0) ? 0.125f : 1.0f;
        #pragma unroll
        for (int i = 0; i < 4; i++) {
            int gm = r0 + wm * 64 + i * 16 + ln15;
            int bb = gm >> 11, mm = gm & 2047;
            #pragma unroll
            for (int j = 0; j < 2; j++) {
                int d0 = wn * 32 + j * 16 + quad * 4;
                ushort4 pk;
                pk.x = f2bf_bits(acc[i][j][0] * sc);
                pk.y = f2bf_bits(acc[i][j][1] * sc);
                pk.z = f2bf_bits(acc[i][j][2] * sc);
                pk.w = f2bf_bits(acc[i][j][3] * sc);
                *(ushort4*)&dst[((size_t)(bb * NH + h) * MM + mm) * DHd + d0] = pk;
            }
        }
    }
}

// ---------------- MFMA flash attention v3: in-register softmax -------------
// Swapped QK^T at 32x32 (S^T = mfma(K, Q)): each lane holds P for 16 keys of
// one q-column. exp -> v_cvt_pk_bf16 -> 2x v_permlane32_swap builds the PV
// P-fragment entirely in registers: sP eliminated (was 32 ds_write_b16 +
// 4 ds_read_b128 per wave per tile). PV = mfma(VT, P) -> O^T, ushort4 stores.
// V extended to 96 rows: 64..66 = key xyz, 67 = 1.0 (gives l), 68..95 = 0.
// K/V/xyz prefetched into VGPRs during compute. SPLITK=3 -> grid 768 = 3/CU.
__global__ __launch_bounds__(256, 3) void attn_kernel(
    const unsigned short* __restrict__ qg, const unsigned short* __restrict__ kg,
    const unsigned short* __restrict__ vg, const float* __restrict__ xyzs,
    unsigned short* __restrict__ obuf, float* __restrict__ lbuf)
{
    __shared__ __align__(16) unsigned short sK[64 * 72];
    __shared__ __align__(16) unsigned short sVT[96 * 72];

    int tid = threadIdx.x;
    int bh = blockIdx.y; int bb = bh >> 3;
    int i0 = blockIdx.x * 128;
    int ks = blockIdx.z;
    int w = tid >> 6;
    int lane = tid & 63;
    int ln31 = lane & 31;
    int hi   = lane >> 5;
    int hi8  = hi * 8;

    // one-time inits: zero pad rows 68..95, ones row 67
    for (int e = tid; e < 28 * 72; e += 256) sVT[68 * 72 + e] = 0;
    if (tid < 64) sVT[67 * 72 + tid] = 0x3F80;   // bf16 1.0

    // Q fragments direct from global (B-operand: lane&31 = q row, hi = k-grp)
    bf16x8 aq[4];
    {
        const unsigned short* q0 = qg + ((size_t)bh * MM + i0 + w * 32 + ln31) * DHd + hi8;
        #pragma unroll
        for (int kc = 0; kc < 4; kc++)
            aq[kc] = *(const bf16x8*)(q0 + kc * 16);
    }

    f32x16 ot[3] = {};   // O^T: vb 0,1 = V cols; vb 2 = [x,y,z,l,0...]

    const unsigned short* kbase = kg + (size_t)bh * MM * DHd;
    const unsigned short* vbase = vg + (size_t)bh * DHd * MM;
    int jbeg = ks * 704;
    int jend = (ks == 2) ? MM : jbeg + 704;

    int srow = tid >> 2, scol16 = (tid & 3) * 16;   // staging coords (K and VT)

    us8 rk0, rk1, rv0, rv1;
    float rx = 0.f;
    {   // preload first tile
        const unsigned short* src = kbase + (size_t)jbeg * DHd;
        rk0 = *(const us8*)&src[(size_t)tid * 16];
        rk1 = *(const us8*)&src[(size_t)tid * 16 + 8];
        const unsigned short* vs = vbase + jbeg;
        rv0 = *(const us8*)&vs[(size_t)srow * MM + scol16];
        rv1 = *(const us8*)&vs[(size_t)srow * MM + scol16 + 8];
        if (tid < 192) rx = xyzs[((size_t)bb * MM + jbeg) * 3 + tid];
    }

    for (int jt = jbeg; jt < jend; jt += 64) {
        __syncthreads();
        // commit prefetched tile to LDS
        *(us8*)&sK[srow * 72 + scol16]      = rk0;
        *(us8*)&sK[srow * 72 + scol16 + 8]  = rk1;
        *(us8*)&sVT[srow * 72 + scol16]     = rv0;
        *(us8*)&sVT[srow * 72 + scol16 + 8] = rv1;
        if (tid < 192) {
            int key = tid / 3, c = tid - key * 3;
            sVT[(64 + c) * 72 + key] = f2bf_bits(rx);
        }
        __syncthreads();
        // issue prefetch for next tile (consumed next iteration)
        int jn = jt + 64;
        if (jn < jend) {
            const unsigned short* src = kbase + (size_t)jn * DHd;
            rk0 = *(const us8*)&src[(size_t)tid * 16];
            rk1 = *(const us8*)&src[(size_t)tid * 16 + 8];
            const unsigned short* vs = vbase + jn;
            rv0 = *(const us8*)&vs[(size_t)srow * MM + scol16];
            rv1 = *(const us8*)&vs[(size_t)srow * MM + scol16 + 8];
            if (tid < 192) rx = xyzs[((size_t)bb * MM + jn) * 3 + tid];
        }

        // two 32-key blocks per tile
        #pragma unroll
        for (int b = 0; b < 2; b++) {
            // S^T[key][q] over DH in 4 chunks of 16
            f32x16 zz = {};
            #pragma unroll
            for (int kc = 0; kc < 4; kc++) {
                bf16x8 kf = *(const bf16x8*)&sK[(b * 32 + ln31) * 72 + kc * 16 + hi8];
                zz = __builtin_amdgcn_mfma_f32_32x32x16_bf16(kf, aq[kc], zz, 0, 0, 0);
            }
            // exp + pack pairs: c[j] = bf16(p[2j]) | bf16(p[2j+1])<<16
            unsigned c_[8];
            #pragma unroll
            for (int j = 0; j < 8; j++)
                c_[j] = cvtpk_bf16(__expf(zz[2 * j]), __expf(zz[2 * j + 1]));
            // build PV P-fragments for the two 16-key k-steps (pure VALU)
            unsigned x0 = c_[0], x2 = c_[2]; pl32swap(x0, x2);
            unsigned x1 = c_[1], x3 = c_[3]; pl32swap(x1, x3);
            unsigned y0 = c_[4], y2 = c_[6]; pl32swap(y0, y2);
            unsigned y1 = c_[5], y3 = c_[7]; pl32swap(y1, y3);
            u32x4 xv = {x0, x1, x2, x3};
            u32x4 yv = {y0, y1, y2, y3};
            bf16x8 X = *(bf16x8*)&xv;
            bf16x8 Y = *(bf16x8*)&yv;
            // PV: O^T[vcol][q] accumulate; A = VT rows (vcol), B = P (q, keys)
            #pragma unroll
            for (int vb = 0; vb < 3; vb++) {
                bf16x8 v0 = *(const bf16x8*)&sVT[(vb * 32 + ln31) * 72 + b * 32 + hi8];
                bf16x8 v1 = *(const bf16x8*)&sVT[(vb * 32 + ln31) * 72 + b * 32 + 16 + hi8];
                ot[vb] = __builtin_amdgcn_mfma_f32_32x32x16_bf16(v0, X, ot[vb], 0, 0, 0);
                ot[vb] = __builtin_amdgcn_mfma_f32_32x32x16_bf16(v1, Y, ot[vb], 0, 0, 0);
            }
        }
    }

    // ---- store partials (unnormalized O and l; merge just sums)
    // lane (hi, ln31=q): ot[vb] reg r -> vcol vb*32 + (r&3) + 8*(r>>2) + 4*hi
    size_t kso = (size_t)ks * NROW;
    size_t row = (size_t)bh * MM + i0 + w * 32 + ln31;
    unsigned short* orow = obuf + (kso + row) * 72;
    #pragma unroll
    for (int vb = 0; vb < 2; vb++) {
        #pragma unroll
        for (int rq = 0; rq < 4; rq++) {
            ushort4 pk;
            pk.x = f2bf_bits(ot[vb][rq * 4 + 0]);
            pk.y = f2bf_bits(ot[vb][rq * 4 + 1]);
            pk.z = f2bf_bits(ot[vb][rq * 4 + 2]);
            pk.w = f2bf_bits(ot[vb][rq * 4 + 3]);
            *(ushort4*)&orow[vb * 32 + rq * 8 + hi * 4] = pk;
        }
    }
    if (hi == 0) {
        orow[64] = f2bf_bits(ot[2][0]);   // x agg
        orow[65] = f2bf_bits(ot[2][1]);   // y agg
        orow[66] = f2bf_bits(ot[2][2]);   // z agg
        lbuf[kso + row] = ot[2][3];       // l (fp32)
    }
}

// ---------------- merge 3 split-K partials + w_sp epilogue -> bf16 ---------
__global__ __launch_bounds__(256) void merge_kernel(
    const unsigned short* __restrict__ obuf, const float* __restrict__ lbuf,
    const float* __restrict__ xyzs, const float* __restrict__ wsp,
    unsigned short* __restrict__ attn_out)
{
    __shared__ float sW[3][64];
    int tid = threadIdx.x;
    if (tid < 192) sW[tid >> 6][tid & 63] = wsp[tid];
    __syncthreads();
    int r   = blockIdx.x * 64 + (tid >> 2);
    int d0  = (tid & 3) * 16;
    int bh = r >> 11, qrow = r & 2047, bb = bh >> 3, hh = bh & 7;
    const unsigned short* p0 = obuf + (size_t)r * 72;
    const unsigned short* p1 = p0 + (size_t)NROW * 72;
    const unsigned short* p2 = p1 + (size_t)NROW * 72;
    float invl = 1.f / (lbuf[r] + lbuf[NROW + r] + lbuf[2 * NROW + r]);
    size_t xb = ((size_t)bb * MM + qrow) * 3;
    float gx = (bf2f(p0[64]) + bf2f(p1[64]) + bf2f(p2[64])) * invl - xyzs[xb + 0];
    float gy = (bf2f(p0[65]) + bf2f(p1[65]) + bf2f(p2[65])) * invl - xyzs[xb + 1];
    float gz = (bf2f(p0[66]) + bf2f(p1[66]) + bf2f(p2[66])) * invl - xyzs[xb + 2];
    us8 a0 = *(const us8*)&p0[d0];
    us8 a1 = *(const us8*)&p0[d0 + 8];
    us8 b0 = *(const us8*)&p1[d0];
    us8 b1 = *(const us8*)&p1[d0 + 8];
    us8 c0 = *(const us8*)&p2[d0];
    us8 c1 = *(const us8*)&p2[d0 + 8];
    unsigned short outv[16];
    #pragma unroll
    for (int e = 0; e < 8; e++) {
        int d = d0 + e;
        float v = (bf2f(a0[e]) + bf2f(b0[e]) + bf2f(c0[e])) * invl
                + gx * sW[0][d] + gy * sW[1][d] + gz * sW[2][d];
        outv[e] = f2bf_bits(v);
    }
    #pragma unroll
    for (int e = 0; e < 8; e++) {
        int d = d0 + 8 + e;
        float v = (bf2f(a1[e]) + bf2f(b1[e]) + bf2f(c1[e])) * invl
                + gx * sW[0][d] + gy * sW[1][d] + gz * sW[2][d];
        outv[8 + e] = f2bf_bits(v);
    }
    unsigned short* dst = attn_out + ((size_t)bb * MM + qrow) * DIM + hh * DHd + d0;
    *(us8*)dst       = *(us8*)&outv[0];
    *(us8*)(dst + 8) = *(us8*)&outv[8];
}

// ---- out GEMM v2: 64x64 tiles, BK=64, register prefetch
//      bf16 A @ bf16 BT^T + bias + exact GeLU + residual -> fp32
__global__ __launch_bounds__(256) void out_gemm(
    const unsigned short* __restrict__ A, const unsigned short* __restrict__ BT,
    const float* __restrict__ bias, const float* __restrict__ feat,
    float* __restrict__ out)
{
    __shared__ __align__(16) unsigned short sA[64 * 72];
    __shared__ __align__(16) unsigned short sB[64 * 72];
    int tid = threadIdx.x;
    int r0 = blockIdx.x * 64, n0 = blockIdx.y * 64;
    int w = tid >> 6, lane = tid & 63;
    int wm = w >> 1, wn = w & 1;
    int ln15 = lane & 15, quad = lane >> 4;

    int srow = tid >> 2, scol = (tid & 3) * 16;   // 64 rows x 64 cols stage

    f32x4 acc[2][2] = {};
    us8 ra[2], rb[2];

    #pragma unroll
    for (int u = 0; u < 2; u++) {
        ra[u] = *(const us8*)&A[(size_t)(r0 + srow) * DIM + scol + u * 8];
        rb[u] = *(const us8*)&BT[(size_t)(n0 + srow) * DIM + scol + u * 8];
    }

    for (int k0 = 0; k0 < DIM; k0 += 64) {
        __syncthreads();
        #pragma unroll
        for (int u = 0; u < 2; u++) {
            *(us8*)&sA[srow * 72 + scol + u * 8] = ra[u];
            *(us8*)&sB[srow * 72 + scol + u * 8] = rb[u];
        }
        __syncthreads();
        int kn = k0 + 64;
        if (kn < DIM) {
            #pragma unroll
            for (int u = 0; u < 2; u++) {
                ra[u] = *(const us8*)&A[(size_t)(r0 + srow) * DIM + kn + scol + u * 8];
                rb[u] = *(const us8*)&BT[(size_t)(n0 + srow) * DIM + kn + scol + u * 8];
            }
        }
        bf16x8 af[2][2], bf_[2][2];
        #pragma unroll
        for (int i = 0; i < 2; i++)
            #pragma unroll
            for (int kk = 0; kk < 2; kk++)
                af[i][kk] = *(const bf16x8*)&sA[(wm * 32 + i * 16 + ln15) * 72 + kk * 32 + quad * 8];
        #pragma unroll
        for (int j = 0; j < 2; j++)
            #pragma unroll
            for (int kk = 0; kk < 2; kk++)
                bf_[j][kk] = *(const bf16x8*)&sB[(wn * 32 + j * 16 + ln15) * 72 + kk * 32 + quad * 8];
        #pragma unroll
        for (int kk = 0; kk < 2; kk++)
            #pragma unroll
            for (int i = 0; i < 2; i++)
                #pragma unroll
                for (int j = 0; j < 2; j++)
                    acc[i][j] = __builtin_amdgcn_mfma_f32_16x16x32_bf16(af[i][kk], bf_[j][kk], acc[i][j], 0, 0, 0);
    }

    #pragma unroll
    for (int i = 0; i < 2; i++) {
        #pragma unroll
        for (int reg = 0; reg < 4; reg++) {
            int gr = r0 + wm * 32 + i * 16 + quad * 4 + reg;
            #pragma unroll
            for (int j = 0; j < 2; j++) {
                int c = n0 + wn * 32 + j * 16 + ln15;
                float x = acc[i][j][reg] + bias[c];
                float g = 0.5f * x * (1.f + erff(x * 0.70710678118f));
                out[(size_t)gr * DIM + c] = g + feat[(size_t)gr * DIM + c];
            }
        }
    }
}

extern "C" void kernel_launch(void* const* d_in, const int* in_sizes, int n_in,
                              void* d_out, int out_size, void* d_ws, size_t ws_size,
                              hipStream_t stream)
{
    const float* xyzs  = (const float*)d_in[0];
    const float* feat  = (const float*)d_in[1];
    const float* gamma = (const float*)d_in[2];
    const float* beta  = (const float*)d_in[3];
    const float* wqkv  = (const float*)d_in[4];
    const float* wsp   = (const float*)d_in[5];
    const float* wout  = (const float*)d_in[6];
    const float* bout  = (const float*)d_in[7];
    float* out = (float*)d_out;

    unsigned short* ws16 = (unsigned short*)d_ws;
    const size_t SEGS = (size_t)ROWS * DIM;              // 2,097,152 shorts (4 MB)
    unsigned short* normed = ws16;                       // reused as attn_out
    unsigned short* qb     = ws16 + SEGS;
    unsigned short* kb     = ws16 + 2 * SEGS;
    unsigned short* vb     = ws16 + 3 * SEGS;
    unsigned short* wqkvT  = ws16 + 4 * SEGS;            // 786,432 shorts
    unsigned short* woutT  = wqkvT + (size_t)NQK * DIM;  // 262,144 shorts
    unsigned short* obuf   = woutT + (size_t)DIM * DIM;  // 3*32768*72 shorts (14.2 MB)
    float*          lbuf   = (float*)(obuf + (size_t)SPLITK * NROW * 72); // 3*32768 f32

    pre_kernel<<<ROWS / 4 + 256, 256, 0, stream>>>(feat, gamma, beta, normed,
                                                   wqkv, wout, wqkvT, woutT);
    qkv_gemm<<<dim3(32, 24), 256, 0, stream>>>(normed, wqkvT, qb, kb, vb);
    attn_kernel<<<dim3(16, 16, SPLITK), 256, 0, stream>>>(qb, kb, vb, xyzs, obuf, lbuf);
    merge_kernel<<<512, 256, 0, stream>>>(obuf, lbuf, xyzs, wsp, normed);
    out_gemm<<<dim3(64, 8), 256, 0, stream>>>(normed, woutT, bout, feat, out);
}